// Round 6
// baseline (430.225 us; speedup 1.0000x reference)
//
#include <hip/hip_runtime.h>
#include <hip/hip_bf16.h>

#define NNODES 50000
#define NEDGES 800000
#define HID 256
#define BN_EPS 1e-5f
#define SCAN_B ((NNODES + 255) / 256)   // 196 blocks

typedef __attribute__((ext_vector_type(8))) short short8v;
typedef __attribute__((ext_vector_type(4))) float f32x4;
typedef __attribute__((ext_vector_type(2))) float f32x2;

__device__ inline void load_lds16(const void* g, void* l) {
    __builtin_amdgcn_global_load_lds(
        (const __attribute__((address_space(1))) unsigned int*)g,
        (__attribute__((address_space(3))) unsigned int*)l, 16, 0, 0);
}

// ---------------- CSR build ----------------
__global__ void k_countrank(const int* __restrict__ ei, int* __restrict__ cnt,
                            int* __restrict__ rank, int nE) {
    int e = blockIdx.x * blockDim.x + threadIdx.x;
    if (e < nE) rank[e] = atomicAdd(&cnt[ei[nE + e]], 1);
}

__global__ void k_bsum(const int* __restrict__ cnt, int* __restrict__ loc,
                       int* __restrict__ bsum, int n) {
    __shared__ int sh[256];
    int tid = threadIdx.x;
    int i = blockIdx.x * 256 + tid;
    int v = (i < n) ? cnt[i] : 0;
    sh[tid] = v;
    __syncthreads();
    for (int off = 1; off < 256; off <<= 1) {
        int t = (tid >= off) ? sh[tid - off] : 0;
        __syncthreads();
        sh[tid] += t;
        __syncthreads();
    }
    if (i < n) loc[i] = sh[tid] - v;
    if (tid == 255) bsum[blockIdx.x] = sh[255];
}

__global__ void k_bscan(int* __restrict__ bsum, int nb) {
    __shared__ int sh[256];
    int tid = threadIdx.x;
    int v = (tid < nb) ? bsum[tid] : 0;
    sh[tid] = v;
    __syncthreads();
    for (int off = 1; off < 256; off <<= 1) {
        int t = (tid >= off) ? sh[tid - off] : 0;
        __syncthreads();
        sh[tid] += t;
        __syncthreads();
    }
    if (tid < nb) bsum[tid] = sh[tid] - v;
}

__global__ void k_addoff(const int* __restrict__ loc, const int* __restrict__ bsum,
                         int* __restrict__ rowptr, int n, int nE) {
    int i = blockIdx.x * 256 + threadIdx.x;
    if (i < n) rowptr[i] = loc[i] + bsum[blockIdx.x];
    if (i == 0) rowptr[n] = nE;
}

__global__ void k_fill2(const int* __restrict__ ei, const int* __restrict__ rowptr,
                        const int* __restrict__ rank, int* __restrict__ col, int nE) {
    int e = blockIdx.x * blockDim.x + threadIdx.x;
    if (e < nE) col[rowptr[ei[nE + e]] + rank[e]] = ei[e];
}

// ---------------- fused prep: cast x->bf16+fp8, pack weights, zero cnt ------
// Weights are written in the GEMM's LDS-staging order so the per-step
// global_load_lds is perfectly linear:
//   packed[((k/8)*256 + col)*8 + (k&7)]  (per matrix; W1 then W2 stacked)
// ranges: [0,1600000) cast float4 ; [.., +327680) pack ; [.., +50000) zero
#define PREP_CAST 1600000
#define PREP_TR   327680
__global__ void k_prep(const float* __restrict__ x,
                       __hip_bfloat16* __restrict__ xb, unsigned char* __restrict__ x8,
                       const float* __restrict__ s0, const float* __restrict__ s1,
                       const float* __restrict__ s2, const float* __restrict__ s3,
                       const float* __restrict__ s4, const float* __restrict__ s5,
                       __hip_bfloat16* __restrict__ d0, __hip_bfloat16* __restrict__ d1,
                       __hip_bfloat16* __restrict__ d2, __hip_bfloat16* __restrict__ d3,
                       __hip_bfloat16* __restrict__ d4, __hip_bfloat16* __restrict__ d5,
                       int* __restrict__ cnt) {
    int f = blockIdx.x * blockDim.x + threadIdx.x;
    if (f < PREP_CAST) {
        float4 v = *(const float4*)(x + f * 4);
        union { uint2 u; unsigned short s[4]; } ob;
        ob.s[0] = __bfloat16_as_ushort(__float2bfloat16(v.x));
        ob.s[1] = __bfloat16_as_ushort(__float2bfloat16(v.y));
        ob.s[2] = __bfloat16_as_ushort(__float2bfloat16(v.z));
        ob.s[3] = __bfloat16_as_ushort(__float2bfloat16(v.w));
        *(uint2*)(xb + f * 4) = ob.u;
        int p = __builtin_amdgcn_cvt_pk_fp8_f32(v.x, v.y, 0, false);
        p = __builtin_amdgcn_cvt_pk_fp8_f32(v.z, v.w, p, true);
        *(int*)(x8 + f * 4) = p;
    } else if (f < PREP_CAST + PREP_TR) {
        int r = f - PREP_CAST;
        const float* src; __hip_bfloat16* dst; int i;
        if (r < 65536) {
            if (r < 32768) { src = s0; dst = d0; i = r; }
            else           { src = s1; dst = d1; i = r - 32768; }
        } else {
            int q = r - 65536;
            int wsel = q >> 16;
            i = q & 65535;
            src = (wsel == 0) ? s2 : (wsel == 1) ? s3 : (wsel == 2) ? s4 : s5;
            dst = (wsel == 0) ? d2 : (wsel == 1) ? d3 : (wsel == 2) ? d4 : d5;
        }
        int k = i >> 8;       // source row (din index)
        int nn = i & 255;     // output col
        dst[((k >> 3) * 256 + nn) * 8 + (k & 7)] = __float2bfloat16(src[i]);
    } else {
        int i = f - PREP_CAST - PREP_TR;
        if (i < NNODES) cnt[i] = 0;
    }
}

// ---------------- fused gather-mean + GEMM + BN (+ReLU) ---------------------
// Per block (128 rows x all 256 cols, 1024 threads = 16 waves):
//  phase 0: issue B0 stage (DMA rides under the gather)
//  phase 1: gather-mean this block's 128 nodes from the fp8 table into an
//           XOR-swizzled bf16 A1 tile in LDS (meanf8's inner loop, 8
//           nodes/wave); one __syncthreads (drains vmcnt -> B0 resident too)
//  phase 2: r5-proven 2-barrier B-streaming GEMM; A1 frags via swizzled
//           ds_read (short latency), A2 frags per-lane global with depth-1
//           register prefetch; stage B(s+1) into the other dbuf each step.
//  epilogue: BN -> per-wave XOR-swizzled LDS transpose -> wide stores
//           (+ optional fp8 copy for the next layer's gather table).
// All sync is __syncthreads(); no manual waitcnt.
template <int KH, typename OutT, int RELU, int W8>
__launch_bounds__(1024, 4)
__global__ void k_fused(const unsigned char* __restrict__ gtab,   // fp8 [n,KH]
                        const __hip_bfloat16* __restrict__ A2,    // bf16 [n,KH]
                        const __hip_bfloat16* __restrict__ Wp,    // packed [W1;W2]
                        const int* __restrict__ rowptr, const int* __restrict__ col,
                        const float* __restrict__ bl,
                        const float* __restrict__ g,
                        const float* __restrict__ bb,
                        const float* __restrict__ rm,
                        const float* __restrict__ rv,
                        OutT* __restrict__ out, unsigned char* __restrict__ out8,
                        int n) {
    constexpr int NSTEP = KH / 16;        // K-steps of 32 over [W1;W2]
    constexpr int NH = NSTEP / 2;         // first half = A1(mean)@W1
    constexpr int ROWB = KH * 2;          // A1 row bytes (bf16)
    constexpr int A1SZ = 128 * ROWB;      // 32KB (KH=128) / 64KB (KH=256)
    __shared__ char lds[A1SZ + 32768];    // A1 tile + 2x16KB B dbuf
    char* bbase = lds + A1SZ;
    int tid = threadIdx.x, rb = blockIdx.x;
    int lane = tid & 63, wv = tid >> 6;
    int quad = lane >> 4, ml = lane & 15;

    // ---- phase 0: pre-stage B0 (lands during gather)
    load_lds16((const char*)Wp + tid * 16, bbase + tid * 16);

    // ---- phase 1: gather-mean 8 nodes per wave -> swizzled A1 tile
    {
        constexpr int CPL = KH / 16;      // lanes per row (16B fp8 each)
        constexpr int R = 64 / CPL;       // neighbor slots per sub-step
        constexpr int U = (KH == 128) ? 2 : 4;
        int sub = lane / CPL, fpos = lane % CPL;
        const uint4* base = (const uint4*)gtab;
        for (int kk = 0; kk < 8; kk++) {
            int rowl = wv * 8 + kk;
            int nd = rb * 128 + rowl;
            int beg = 0, end = 0;
            if (nd < n) { beg = rowptr[nd]; end = rowptr[nd + 1]; }
            float acc[16];
#pragma unroll
            for (int j = 0; j < 16; j++) acc[j] = 0.f;
            for (int p0 = beg; p0 < end; p0 += U * R) {
                int idx[U]; bool ok[U];
#pragma unroll
                for (int u = 0; u < U; u++) {
                    int p = p0 + u * R + sub;
                    ok[u] = (p < end);
                    idx[u] = ok[u] ? col[p] : 0;
                }
                uint4 v[U];
#pragma unroll
                for (int u = 0; u < U; u++) {
                    uint4 t = {0u, 0u, 0u, 0u};
                    if (ok[u]) t = base[(size_t)idx[u] * CPL + fpos];
                    v[u] = t;
                }
#pragma unroll
                for (int u = 0; u < U; u++) {
                    const unsigned int uu[4] = {v[u].x, v[u].y, v[u].z, v[u].w};
#pragma unroll
                    for (int q = 0; q < 4; q++) {
                        f32x2 lo = __builtin_amdgcn_cvt_pk_f32_fp8(uu[q], false);
                        f32x2 hi = __builtin_amdgcn_cvt_pk_f32_fp8(uu[q], true);
                        acc[4 * q + 0] += lo.x;
                        acc[4 * q + 1] += lo.y;
                        acc[4 * q + 2] += hi.x;
                        acc[4 * q + 3] += hi.y;
                    }
                }
            }
            if constexpr (R >= 8) {
#pragma unroll
                for (int j = 0; j < 16; j++) acc[j] += __shfl_xor(acc[j], 8, 64);
            }
#pragma unroll
            for (int j = 0; j < 16; j++) acc[j] += __shfl_xor(acc[j], 16, 64);
#pragma unroll
            for (int j = 0; j < 16; j++) acc[j] += __shfl_xor(acc[j], 32, 64);
            if (sub == 0) {
                float inv = (end > beg) ? 1.f / (float)(end - beg) : 0.f;
                union { uint4 v[2]; unsigned short s[16]; } o;
#pragma unroll
                for (int j = 0; j < 16; j++)
                    o.s[j] = __bfloat16_as_ushort(__float2bfloat16(acc[j] * inv));
                char* rp = lds + (size_t)rowl * ROWB;
                *(uint4*)(rp + ((2 * fpos + 0) ^ (rowl & 15)) * 16) = o.v[0];
                *(uint4*)(rp + ((2 * fpos + 1) ^ (rowl & 15)) * 16) = o.v[1];
            }
        }
    }
    __syncthreads();   // A1 tile complete; vmcnt drained -> B0 resident

    // ---- phase 2: GEMM over stacked K (A1@W1 first half, A2@W2 second)
    int wr = wv >> 2, wc = wv & 3;        // 4 row-groups x 4 col-groups
    int row0 = rb * 128 + wr * 32;

    const short8v* p2[2];
#pragma unroll
    for (int i = 0; i < 2; i++) {
        int r = row0 + i * 16 + ml;
        if (r > n - 1) r = n - 1;
        p2[i] = (const short8v*)(A2 + (size_t)r * KH) + quad;
    }

    f32x4 acc[2][4];
#pragma unroll
    for (int i = 0; i < 2; i++)
#pragma unroll
        for (int t = 0; t < 4; t++) acc[i][t] = {0.f, 0.f, 0.f, 0.f};

    short8v ab[2][2];
    const char* wpb = (const char*)Wp;

#pragma unroll
    for (int s = 0; s < NSTEP; s++) {
        char* buf  = bbase + (s & 1) * 16384;
        char* nbuf = bbase + ((s + 1) & 1) * 16384;
        if (s + 1 < NSTEP) {
            load_lds16(wpb + (size_t)(s + 1) * 16384 + tid * 16, nbuf + tid * 16);
            if (s + 1 >= NH) {            // prefetch next A2 fragments
                int sh = s + 1 - NH;
                ab[(s + 1) & 1][0] = p2[0][sh * 4];
                ab[(s + 1) & 1][1] = p2[1][sh * 4];
            }
        }
        short8v af0, af1;
        if (s < NH) {                      // A1 fragments from swizzled LDS
            int c = s * 4 + quad;
            int r0l = wr * 32 + ml;
            int r1l = wr * 32 + 16 + ml;
            af0 = *(const short8v*)(lds + (size_t)r0l * ROWB + ((c ^ (r0l & 15)) * 16));
            af1 = *(const short8v*)(lds + (size_t)r1l * ROWB + ((c ^ (r1l & 15)) * 16));
        } else {
            af0 = ab[s & 1][0];
            af1 = ab[s & 1][1];
        }
        short8v bfr[4];
#pragma unroll
        for (int t = 0; t < 4; t++)
            bfr[t] = *(const short8v*)(
                buf + (size_t)((quad * 256) + (wc * 64 + t * 16 + ml)) * 16);
#pragma unroll
        for (int t = 0; t < 4; t++) {
            acc[0][t] = __builtin_amdgcn_mfma_f32_16x16x32_bf16(af0, bfr[t], acc[0][t], 0, 0, 0);
            acc[1][t] = __builtin_amdgcn_mfma_f32_16x16x32_bf16(af1, bfr[t], acc[1][t], 0, 0, 0);
        }
        __syncthreads();   // B(s+1) landed; buf reads done
    }

    // ---- epilogue: BN -> per-wave swizzled LDS transpose -> wide stores ----
    char* scrb = lds + wv * 4096;         // 16 rows x 64 cols f32 per wave
    float sv[4], tv[4];
#pragma unroll
    for (int t = 0; t < 4; t++) {
        int c = wc * 64 + t * 16 + ml;
        sv[t] = g[c] * rsqrtf(rv[c] + BN_EPS);
        tv[t] = (bl[c] - rm[c]) * sv[t] + bb[c];
    }
    int rl8 = lane >> 3, c8 = (lane & 7) * 8;
#pragma unroll
    for (int p = 0; p < 2; p++) {
#pragma unroll
        for (int t = 0; t < 4; t++) {
#pragma unroll
            for (int r = 0; r < 4; r++) {
                float v = acc[p][t][r] * sv[t] + tv[t];
                if (RELU) v = fmaxf(v, 0.f);
                int rowl = quad * 4 + r;
                int off = rowl * 256 + (((t * 16 + ml) * 4) ^ ((rowl & 7) << 4));
                *(float*)(scrb + off) = v;
            }
        }
        // same-wave ds_write -> ds_read: compiler inserts the lgkmcnt wait
#pragma unroll
        for (int q = 0; q < 2; q++) {
            int rowl = q * 8 + rl8;
            int row = row0 + p * 16 + rowl;
            int sw = (rowl & 7) << 4;
            f32x4 v0 = *(const f32x4*)(scrb + rowl * 256 + ((c8 * 4) ^ sw));
            f32x4 v1 = *(const f32x4*)(scrb + rowl * 256 + ((c8 * 4 + 16) ^ sw));
            if (row < n) {
                int c0 = wc * 64 + c8;
                if constexpr (sizeof(OutT) == 2) {
                    union { uint4 u; unsigned short s[8]; } o;
                    o.s[0] = __bfloat16_as_ushort(__float2bfloat16(v0.x));
                    o.s[1] = __bfloat16_as_ushort(__float2bfloat16(v0.y));
                    o.s[2] = __bfloat16_as_ushort(__float2bfloat16(v0.z));
                    o.s[3] = __bfloat16_as_ushort(__float2bfloat16(v0.w));
                    o.s[4] = __bfloat16_as_ushort(__float2bfloat16(v1.x));
                    o.s[5] = __bfloat16_as_ushort(__float2bfloat16(v1.y));
                    o.s[6] = __bfloat16_as_ushort(__float2bfloat16(v1.z));
                    o.s[7] = __bfloat16_as_ushort(__float2bfloat16(v1.w));
                    *(uint4*)(out + (size_t)row * HID + c0) = o.u;
                } else {
                    float* dst = (float*)out + (size_t)row * HID + c0;
                    *(f32x4*)dst = v0;
                    *(f32x4*)(dst + 4) = v1;
                }
                if constexpr (W8) {
                    int lo = __builtin_amdgcn_cvt_pk_fp8_f32(v0.x, v0.y, 0, false);
                    lo = __builtin_amdgcn_cvt_pk_fp8_f32(v0.z, v0.w, lo, true);
                    int hi = __builtin_amdgcn_cvt_pk_fp8_f32(v1.x, v1.y, 0, false);
                    hi = __builtin_amdgcn_cvt_pk_fp8_f32(v1.z, v1.w, hi, true);
                    uint2 u2 = {(unsigned)lo, (unsigned)hi};
                    *(uint2*)(out8 + (size_t)row * HID + c0) = u2;
                }
            }
        }
    }
}

extern "C" void kernel_launch(void* const* d_in, const int* in_sizes, int n_in,
                              void* d_out, int out_size, void* d_ws, size_t ws_size,
                              hipStream_t stream) {
    const float* x = (const float*)d_in[0];
    const int* ei = (const int*)d_in[1];
    const float *Wl[3], *blv[3], *Wr[3], *g[3], *bb[3], *rm[3], *rv[3];
    for (int i = 0; i < 3; i++) {
        int b = 2 + i * 7;
        Wl[i]  = (const float*)d_in[b + 0];
        blv[i] = (const float*)d_in[b + 1];
        Wr[i]  = (const float*)d_in[b + 2];
        g[i]   = (const float*)d_in[b + 3];
        bb[i]  = (const float*)d_in[b + 4];
        rm[i]  = (const float*)d_in[b + 5];
        rv[i]  = (const float*)d_in[b + 6];
    }

    // scratch inside d_out (fully overwritten by the final GEMM):
    char* ob = (char*)d_out;
    __hip_bfloat16* xb = (__hip_bfloat16*)ob;                              // 12.8 MB
    __hip_bfloat16* h0 = (__hip_bfloat16*)(ob + (size_t)NNODES * 128 * 2); // 25.6 MB

    char* w = (char*)d_ws;
    size_t off = 0;
    auto alloc = [&](size_t bytes) {
        void* p = w + off;
        off += (bytes + 255) & ~(size_t)255;
        return p;
    };
    int* rowptr = (int*)alloc((NNODES + 1) * sizeof(int));
    int* cnt    = (int*)alloc(NNODES * sizeof(int));
    int* loc    = (int*)alloc(NNODES * sizeof(int));
    int* bsum   = (int*)alloc(SCAN_B * sizeof(int));
    int* rank   = (int*)alloc(NEDGES * sizeof(int));
    int* col    = (int*)alloc(NEDGES * sizeof(int));
    __hip_bfloat16* h1 = (__hip_bfloat16*)alloc((size_t)NNODES * HID * 2);
    unsigned char* x8   = (unsigned char*)alloc((size_t)NNODES * 128);
    unsigned char* h0f8 = (unsigned char*)alloc((size_t)NNODES * HID);
    unsigned char* h1f8 = (unsigned char*)alloc((size_t)NNODES * HID);
    // packed weights, [m][k8][col][8] staging order per layer
    __hip_bfloat16* Wp0 = (__hip_bfloat16*)alloc((size_t)2 * 128 * 256 * 2);
    __hip_bfloat16* Wp1 = (__hip_bfloat16*)alloc((size_t)2 * 256 * 256 * 2);
    __hip_bfloat16* Wp2 = (__hip_bfloat16*)alloc((size_t)2 * 256 * 256 * 2);

    // fused prep: cast x (bf16 + fp8), pack weights, zero cnt
    int prepTotal = PREP_CAST + PREP_TR + NNODES;
    k_prep<<<(prepTotal + 255) / 256, 256, 0, stream>>>(
        x, xb, x8, Wl[0], Wr[0], Wl[1], Wr[1], Wl[2], Wr[2],
        Wp0, Wp0 + 32768, Wp1, Wp1 + 65536, Wp2, Wp2 + 65536, cnt);

    // CSR build
    k_countrank<<<(NEDGES + 255) / 256, 256, 0, stream>>>(ei, cnt, rank, NEDGES);
    k_bsum<<<SCAN_B, 256, 0, stream>>>(cnt, loc, bsum, NNODES);
    k_bscan<<<1, 256, 0, stream>>>(bsum, SCAN_B);
    k_addoff<<<SCAN_B, 256, 0, stream>>>(loc, bsum, rowptr, NNODES, NEDGES);
    k_fill2<<<(NEDGES + 255) / 256, 256, 0, stream>>>(ei, rowptr, rank, col, NEDGES);

    int fusedBlocks = (NNODES + 127) / 128;          // 391 full-width blocks

    // layer 0: gather x8 (D=128) + GEMM(mean@Wl0 + x@Wr0) + BN + ReLU
    k_fused<128, __hip_bfloat16, 1, 1><<<fusedBlocks, 1024, 0, stream>>>(
        x8, xb, Wp0, rowptr, col,
        blv[0], g[0], bb[0], rm[0], rv[0], h0, h0f8, NNODES);

    // layer 1: gather h0f8 (D=256) + GEMM + BN + ReLU
    k_fused<256, __hip_bfloat16, 1, 1><<<fusedBlocks, 1024, 0, stream>>>(
        h0f8, h0, Wp1, rowptr, col,
        blv[1], g[1], bb[1], rm[1], rv[1], h1, h1f8, NNODES);

    // layer 2: gather h1f8 (D=256) + GEMM + BN (no relu) -> f32 d_out
    k_fused<256, float, 0, 0><<<fusedBlocks, 1024, 0, stream>>>(
        h1f8, h1, Wp2, rowptr, col,
        blv[2], g[2], bb[2], rm[2], rv[2], (float*)d_out, (unsigned char*)nullptr, NNODES);
}

// Round 7
// 380.537 us; speedup vs baseline: 1.1306x; 1.1306x over previous
//
#include <hip/hip_runtime.h>
#include <hip/hip_bf16.h>

#define NNODES 50000
#define NEDGES 800000
#define HID 256
#define BN_EPS 1e-5f
#define SCAN_B ((NNODES + 255) / 256)   // 196 blocks

typedef __attribute__((ext_vector_type(8))) short short8v;
typedef __attribute__((ext_vector_type(4))) float f32x4;
typedef __attribute__((ext_vector_type(2))) float f32x2;

__device__ inline void load_lds16(const void* g, void* l) {
    __builtin_amdgcn_global_load_lds(
        (const __attribute__((address_space(1))) unsigned int*)g,
        (__attribute__((address_space(3))) unsigned int*)l, 16, 0, 0);
}

// ---------------- CSR build ----------------
__global__ void k_countrank(const int* __restrict__ ei, int* __restrict__ cnt,
                            int* __restrict__ rank, int nE) {
    int e = blockIdx.x * blockDim.x + threadIdx.x;
    if (e < nE) rank[e] = atomicAdd(&cnt[ei[nE + e]], 1);
}

__global__ void k_bsum(const int* __restrict__ cnt, int* __restrict__ loc,
                       int* __restrict__ bsum, int n) {
    __shared__ int sh[256];
    int tid = threadIdx.x;
    int i = blockIdx.x * 256 + tid;
    int v = (i < n) ? cnt[i] : 0;
    sh[tid] = v;
    __syncthreads();
    for (int off = 1; off < 256; off <<= 1) {
        int t = (tid >= off) ? sh[tid - off] : 0;
        __syncthreads();
        sh[tid] += t;
        __syncthreads();
    }
    if (i < n) loc[i] = sh[tid] - v;
    if (tid == 255) bsum[blockIdx.x] = sh[255];
}

__global__ void k_bscan(int* __restrict__ bsum, int nb) {
    __shared__ int sh[256];
    int tid = threadIdx.x;
    int v = (tid < nb) ? bsum[tid] : 0;
    sh[tid] = v;
    __syncthreads();
    for (int off = 1; off < 256; off <<= 1) {
        int t = (tid >= off) ? sh[tid - off] : 0;
        __syncthreads();
        sh[tid] += t;
        __syncthreads();
    }
    if (tid < nb) bsum[tid] = sh[tid] - v;
}

__global__ void k_addoff(const int* __restrict__ loc, const int* __restrict__ bsum,
                         int* __restrict__ rowptr, int n, int nE) {
    int i = blockIdx.x * 256 + threadIdx.x;
    if (i < n) rowptr[i] = loc[i] + bsum[blockIdx.x];
    if (i == 0) rowptr[n] = nE;
}

__global__ void k_fill2(const int* __restrict__ ei, const int* __restrict__ rowptr,
                        const int* __restrict__ rank, int* __restrict__ col, int nE) {
    int e = blockIdx.x * blockDim.x + threadIdx.x;
    if (e < nE) col[rowptr[ei[nE + e]] + rank[e]] = ei[e];
}

// ---------------- fused prep: cast x->bf16+fp8, pack weights, zero cnt ------
// Weights are written in the GEMM's B-fragment order so per-lane global
// reads are coalesced:  packed[((k/8)*256 + col)*8 + (k&7)]
// (per matrix; W1 then W2 stacked along k8).
// ranges: [0,1600000) cast float4 ; [.., +327680) pack ; [.., +50000) zero
#define PREP_CAST 1600000
#define PREP_TR   327680
__global__ void k_prep(const float* __restrict__ x,
                       __hip_bfloat16* __restrict__ xb, unsigned char* __restrict__ x8,
                       const float* __restrict__ s0, const float* __restrict__ s1,
                       const float* __restrict__ s2, const float* __restrict__ s3,
                       const float* __restrict__ s4, const float* __restrict__ s5,
                       __hip_bfloat16* __restrict__ d0, __hip_bfloat16* __restrict__ d1,
                       __hip_bfloat16* __restrict__ d2, __hip_bfloat16* __restrict__ d3,
                       __hip_bfloat16* __restrict__ d4, __hip_bfloat16* __restrict__ d5,
                       int* __restrict__ cnt) {
    int f = blockIdx.x * blockDim.x + threadIdx.x;
    if (f < PREP_CAST) {
        float4 v = *(const float4*)(x + f * 4);
        union { uint2 u; unsigned short s[4]; } ob;
        ob.s[0] = __bfloat16_as_ushort(__float2bfloat16(v.x));
        ob.s[1] = __bfloat16_as_ushort(__float2bfloat16(v.y));
        ob.s[2] = __bfloat16_as_ushort(__float2bfloat16(v.z));
        ob.s[3] = __bfloat16_as_ushort(__float2bfloat16(v.w));
        *(uint2*)(xb + f * 4) = ob.u;
        int p = __builtin_amdgcn_cvt_pk_fp8_f32(v.x, v.y, 0, false);
        p = __builtin_amdgcn_cvt_pk_fp8_f32(v.z, v.w, p, true);
        *(int*)(x8 + f * 4) = p;
    } else if (f < PREP_CAST + PREP_TR) {
        int r = f - PREP_CAST;
        const float* src; __hip_bfloat16* dst; int i;
        if (r < 65536) {
            if (r < 32768) { src = s0; dst = d0; i = r; }
            else           { src = s1; dst = d1; i = r - 32768; }
        } else {
            int q = r - 65536;
            int wsel = q >> 16;
            i = q & 65535;
            src = (wsel == 0) ? s2 : (wsel == 1) ? s3 : (wsel == 2) ? s4 : s5;
            dst = (wsel == 0) ? d2 : (wsel == 1) ? d3 : (wsel == 2) ? d4 : d5;
        }
        int k = i >> 8;       // source row (din index)
        int nn = i & 255;     // output col
        dst[((k >> 3) * 256 + nn) * 8 + (k & 7)] = __float2bfloat16(src[i]);
    } else {
        int i = f - PREP_CAST - PREP_TR;
        if (i < NNODES) cnt[i] = 0;
    }
}

// ---------------- mean aggregation over fp8 table -> bf16 mean ----------
template <int D, int U>
__global__ void k_meanf8(const unsigned char* __restrict__ x8,
                         const int* __restrict__ rowptr, const int* __restrict__ col,
                         __hip_bfloat16* __restrict__ mean, int n) {
    constexpr int CPL = D / 16;
    constexpr int R = 64 / CPL;
    int gw = (blockIdx.x * blockDim.x + threadIdx.x) >> 6;
    int lane = threadIdx.x & 63;
    if (gw >= n) return;
    int beg = rowptr[gw], end = rowptr[gw + 1];
    int sub = lane / CPL;
    int fpos = lane % CPL;
    const uint4* base = (const uint4*)x8;   // CPL uint4 per row

    float acc[16];
#pragma unroll
    for (int j = 0; j < 16; j++) acc[j] = 0.f;

    for (int p0 = beg; p0 < end; p0 += U * R) {
        int idx[U]; bool ok[U];
#pragma unroll
        for (int u = 0; u < U; u++) {
            int p = p0 + u * R + sub;
            ok[u] = (p < end);
            idx[u] = ok[u] ? col[p] : 0;
        }
        uint4 v[U];
#pragma unroll
        for (int u = 0; u < U; u++) {
            uint4 t = {0u, 0u, 0u, 0u};
            if (ok[u]) t = base[(size_t)idx[u] * CPL + fpos];
            v[u] = t;
        }
#pragma unroll
        for (int u = 0; u < U; u++) {
            const unsigned int uu[4] = {v[u].x, v[u].y, v[u].z, v[u].w};
#pragma unroll
            for (int q = 0; q < 4; q++) {
                f32x2 lo = __builtin_amdgcn_cvt_pk_f32_fp8(uu[q], false);
                f32x2 hi = __builtin_amdgcn_cvt_pk_f32_fp8(uu[q], true);
                acc[4 * q + 0] += lo.x;
                acc[4 * q + 1] += lo.y;
                acc[4 * q + 2] += hi.x;
                acc[4 * q + 3] += hi.y;
            }
        }
    }

    if constexpr (R >= 8) {
#pragma unroll
        for (int j = 0; j < 16; j++) acc[j] += __shfl_xor(acc[j], 8, 64);
    }
#pragma unroll
    for (int j = 0; j < 16; j++) acc[j] += __shfl_xor(acc[j], 16, 64);
#pragma unroll
    for (int j = 0; j < 16; j++) acc[j] += __shfl_xor(acc[j], 32, 64);

    if (sub == 0) {
        float inv = (end > beg) ? 1.f / (float)(end - beg) : 0.f;
        union { uint4 v[2]; unsigned short s[16]; } o;
#pragma unroll
        for (int j = 0; j < 16; j++)
            o.s[j] = __bfloat16_as_ushort(__float2bfloat16(acc[j] * inv));
        uint4* dst = (uint4*)(mean + (size_t)gw * D + fpos * 16);
        dst[0] = o.v[0];
        dst[1] = o.v[1];
    }
}

// ---------------- GEMM + BN (+ReLU): A staged in LDS, B coalesced global ----
// out[n,256] = act( (A1@W1 + A2@W2 + bl - rm) * scale + shift )
//
// Root cause found in r1-r6: per-lane A-fragment global loads (512-B row
// stride) are a 64-line scatter per instruction -> address/request pipe
// saturates at ~2k L2 requests per block-step (~4200 cy/step), which is
// why every schedule variant sat at 48-56us with ALL counters idle.
// Fix (this kernel):
//  - whole A1+A2 tile (128 rows x KH each) staged into LDS ONCE via
//    global_load_lds, coalesced (consecutive lanes = consecutive 16B),
//    with per-row XOR applied on the GLOBAL source (G21) so fragment
//    ds_read_b128 is bank-conflict-free. One __syncthreads after staging.
//  - B fragments read per-lane from packed Wp in GLOBAL memory: in that
//    layout consecutive lanes are consecutive 16B (256-B segments) ->
//    coalesced, L2-resident (<=256KB shared by all blocks); depth-1
//    register prefetch. ZERO barriers in the main loop; no VMEM scatter
//    anywhere; all waits compiler-inserted (race-safe).
//  - wave grid 4x4 (32 rows x 64 cols per wave) and r6-verbatim epilogue.
template <int KH, typename OutT, int RELU, int W8>
__launch_bounds__(1024, 4)
__global__ void k_gemm7(const __hip_bfloat16* __restrict__ A1,
                        const __hip_bfloat16* __restrict__ A2,
                        const __hip_bfloat16* __restrict__ Wp,
                        const float* __restrict__ bl,
                        const float* __restrict__ g,
                        const float* __restrict__ bb,
                        const float* __restrict__ rm,
                        const float* __restrict__ rv,
                        OutT* __restrict__ out, unsigned char* __restrict__ out8,
                        int n) {
    constexpr int NSTEP = KH / 16;        // K-steps of 32 over [W1;W2]
    constexpr int NH = NSTEP / 2;         // first half = A1@W1
    constexpr int CH = KH / 8;            // 16B chunks per A row
    constexpr int ROWB = KH * 2;          // A row bytes (bf16)
    constexpr int ASZ = 128 * ROWB;       // one A tile (32KB / 64KB)
    __shared__ char lds[2 * ASZ];         // A1 | A2 ; epilogue reuses as scratch
    int tid = threadIdx.x, rb = blockIdx.x;
    int lane = tid & 63, wv = tid >> 6;
    int quad = lane >> 4, ml = lane & 15;

    // ---- stage A1+A2 tiles, coalesced, source pre-swizzled by (row&15) ----
#pragma unroll
    for (int it = 0; it < CH / 8; it++) {     // 128*CH/1024 sweeps per matrix
        int j = tid + it * 1024;
        int r = j / CH, c = j % CH;
        int grow = rb * 128 + r; if (grow > n - 1) grow = n - 1;
        int cs = c ^ (r & 15);
        load_lds16(A1 + (size_t)grow * KH + cs * 8, lds + (size_t)j * 16);
        load_lds16(A2 + (size_t)grow * KH + cs * 8, lds + ASZ + (size_t)j * 16);
    }

    int wr = wv >> 2, wc = wv & 3;        // 4 row-groups x 4 col-groups
    int row0 = rb * 128 + wr * 32;

    f32x4 acc[2][4];
#pragma unroll
    for (int i = 0; i < 2; i++)
#pragma unroll
        for (int t = 0; t < 4; t++) acc[i][t] = {0.f, 0.f, 0.f, 0.f};

    // ---- B per-lane coalesced global prefetch (depth 1) ----
    const uint4* wq = (const uint4*)Wp;
    int bch = quad * 256 + wc * 64 + ml;  // + t*16 + s*1024
    uint4 bpre[4];
#pragma unroll
    for (int t = 0; t < 4; t++) bpre[t] = wq[bch + t * 16];

    __syncthreads();                      // A tiles resident (vmcnt drained)

#pragma unroll
    for (int s = 0; s < NSTEP; s++) {
        uint4 bcur[4];
#pragma unroll
        for (int t = 0; t < 4; t++) bcur[t] = bpre[t];
        if (s + 1 < NSTEP) {
#pragma unroll
            for (int t = 0; t < 4; t++)
                bpre[t] = wq[(size_t)(s + 1) * 1024 + bch + t * 16];
        }
        // A fragments from LDS (XOR-swizzled rows)
        const char* areg = (s < NH) ? lds : lds + ASZ;
        int sl = (s < NH) ? s : s - NH;
        short8v af[2];
#pragma unroll
        for (int i = 0; i < 2; i++) {
            int r = wr * 32 + i * 16 + ml;
            int c = sl * 4 + quad;
            af[i] = *(const short8v*)(areg + (size_t)r * ROWB + ((c ^ (r & 15)) << 4));
        }
#pragma unroll
        for (int t = 0; t < 4; t++) {
            short8v bf = *(const short8v*)&bcur[t];
            acc[0][t] = __builtin_amdgcn_mfma_f32_16x16x32_bf16(af[0], bf, acc[0][t], 0, 0, 0);
            acc[1][t] = __builtin_amdgcn_mfma_f32_16x16x32_bf16(af[1], bf, acc[1][t], 0, 0, 0);
        }
    }

    // ---- epilogue: BN -> per-wave swizzled LDS transpose -> wide stores ----
    __syncthreads();                      // all waves done reading A tiles
    char* scrb = lds + wv * 4096;         // 16 rows x 64 cols f32 per wave
    float sv[4], tv[4];
#pragma unroll
    for (int t = 0; t < 4; t++) {
        int c = wc * 64 + t * 16 + ml;
        sv[t] = g[c] * rsqrtf(rv[c] + BN_EPS);
        tv[t] = (bl[c] - rm[c]) * sv[t] + bb[c];
    }
    int rl8 = lane >> 3, c8 = (lane & 7) * 8;
#pragma unroll
    for (int p = 0; p < 2; p++) {
#pragma unroll
        for (int t = 0; t < 4; t++) {
#pragma unroll
            for (int r = 0; r < 4; r++) {
                float v = acc[p][t][r] * sv[t] + tv[t];
                if (RELU) v = fmaxf(v, 0.f);
                int rowl = quad * 4 + r;
                int off = rowl * 256 + (((t * 16 + ml) * 4) ^ ((rowl & 7) << 4));
                *(float*)(scrb + off) = v;
            }
        }
        // same-wave ds_write -> ds_read: compiler inserts the lgkmcnt wait
#pragma unroll
        for (int q = 0; q < 2; q++) {
            int rowl = q * 8 + rl8;
            int row = row0 + p * 16 + rowl;
            int sw = (rowl & 7) << 4;
            f32x4 v0 = *(const f32x4*)(scrb + rowl * 256 + ((c8 * 4) ^ sw));
            f32x4 v1 = *(const f32x4*)(scrb + rowl * 256 + ((c8 * 4 + 16) ^ sw));
            if (row < n) {
                int c0 = wc * 64 + c8;
                if constexpr (sizeof(OutT) == 2) {
                    union { uint4 u; unsigned short s[8]; } o;
                    o.s[0] = __bfloat16_as_ushort(__float2bfloat16(v0.x));
                    o.s[1] = __bfloat16_as_ushort(__float2bfloat16(v0.y));
                    o.s[2] = __bfloat16_as_ushort(__float2bfloat16(v0.z));
                    o.s[3] = __bfloat16_as_ushort(__float2bfloat16(v0.w));
                    o.s[4] = __bfloat16_as_ushort(__float2bfloat16(v1.x));
                    o.s[5] = __bfloat16_as_ushort(__float2bfloat16(v1.y));
                    o.s[6] = __bfloat16_as_ushort(__float2bfloat16(v1.z));
                    o.s[7] = __bfloat16_as_ushort(__float2bfloat16(v1.w));
                    *(uint4*)(out + (size_t)row * HID + c0) = o.u;
                } else {
                    float* dst = (float*)out + (size_t)row * HID + c0;
                    *(f32x4*)dst = v0;
                    *(f32x4*)(dst + 4) = v1;
                }
                if constexpr (W8) {
                    int lo = __builtin_amdgcn_cvt_pk_fp8_f32(v0.x, v0.y, 0, false);
                    lo = __builtin_amdgcn_cvt_pk_fp8_f32(v0.z, v0.w, lo, true);
                    int hi = __builtin_amdgcn_cvt_pk_fp8_f32(v1.x, v1.y, 0, false);
                    hi = __builtin_amdgcn_cvt_pk_fp8_f32(v1.z, v1.w, hi, true);
                    uint2 u2 = {(unsigned)lo, (unsigned)hi};
                    *(uint2*)(out8 + (size_t)row * HID + c0) = u2;
                }
            }
        }
    }
}

extern "C" void kernel_launch(void* const* d_in, const int* in_sizes, int n_in,
                              void* d_out, int out_size, void* d_ws, size_t ws_size,
                              hipStream_t stream) {
    const float* x = (const float*)d_in[0];
    const int* ei = (const int*)d_in[1];
    const float *Wl[3], *blv[3], *Wr[3], *g[3], *bb[3], *rm[3], *rv[3];
    for (int i = 0; i < 3; i++) {
        int b = 2 + i * 7;
        Wl[i]  = (const float*)d_in[b + 0];
        blv[i] = (const float*)d_in[b + 1];
        Wr[i]  = (const float*)d_in[b + 2];
        g[i]   = (const float*)d_in[b + 3];
        bb[i]  = (const float*)d_in[b + 4];
        rm[i]  = (const float*)d_in[b + 5];
        rv[i]  = (const float*)d_in[b + 6];
    }

    // scratch inside d_out (fully overwritten by the final GEMM):
    char* ob = (char*)d_out;
    __hip_bfloat16* xb = (__hip_bfloat16*)ob;                              // 12.8 MB
    __hip_bfloat16* h0 = (__hip_bfloat16*)(ob + (size_t)NNODES * 128 * 2); // 25.6 MB

    char* w = (char*)d_ws;
    size_t off = 0;
    auto alloc = [&](size_t bytes) {
        void* p = w + off;
        off += (bytes + 255) & ~(size_t)255;
        return p;
    };
    int* rowptr = (int*)alloc((NNODES + 1) * sizeof(int));
    int* cnt    = (int*)alloc(NNODES * sizeof(int));
    int* loc    = (int*)alloc(NNODES * sizeof(int));
    int* bsum   = (int*)alloc(SCAN_B * sizeof(int));
    int* rank   = (int*)alloc(NEDGES * sizeof(int));
    int* col    = (int*)alloc(NEDGES * sizeof(int));
    __hip_bfloat16* meanb = (__hip_bfloat16*)alloc((size_t)NNODES * HID * 2);
    __hip_bfloat16* h1    = (__hip_bfloat16*)alloc((size_t)NNODES * HID * 2);
    unsigned char* x8   = (unsigned char*)alloc((size_t)NNODES * 128);
    unsigned char* h0f8 = (unsigned char*)alloc((size_t)NNODES * HID);
    unsigned char* h1f8 = (unsigned char*)alloc((size_t)NNODES * HID);
    // packed weights, [m][k8][col][8] fragment order per layer
    __hip_bfloat16* Wp0 = (__hip_bfloat16*)alloc((size_t)2 * 128 * 256 * 2);
    __hip_bfloat16* Wp1 = (__hip_bfloat16*)alloc((size_t)2 * 256 * 256 * 2);
    __hip_bfloat16* Wp2 = (__hip_bfloat16*)alloc((size_t)2 * 256 * 256 * 2);

    // fused prep: cast x (bf16 + fp8), pack weights, zero cnt
    int prepTotal = PREP_CAST + PREP_TR + NNODES;
    k_prep<<<(prepTotal + 255) / 256, 256, 0, stream>>>(
        x, xb, x8, Wl[0], Wr[0], Wl[1], Wr[1], Wl[2], Wr[2],
        Wp0, Wp0 + 32768, Wp1, Wp1 + 65536, Wp2, Wp2 + 65536, cnt);

    // CSR build
    k_countrank<<<(NEDGES + 255) / 256, 256, 0, stream>>>(ei, cnt, rank, NEDGES);
    k_bsum<<<SCAN_B, 256, 0, stream>>>(cnt, loc, bsum, NNODES);
    k_bscan<<<1, 256, 0, stream>>>(bsum, SCAN_B);
    k_addoff<<<SCAN_B, 256, 0, stream>>>(loc, bsum, rowptr, NNODES, NEDGES);
    k_fill2<<<(NEDGES + 255) / 256, 256, 0, stream>>>(ei, rowptr, rank, col, NEDGES);

    int meanBlocks = (NNODES * 64 + 255) / 256;      // one wave per node
    int gemmBlocks = (NNODES + 127) / 128;           // 391 full-width blocks

    // layer 0 (KH=128): fp8 gather (CPL=8, R=8, U=2 -> 16 in flight)
    k_meanf8<128, 2><<<meanBlocks, 256, 0, stream>>>(x8, rowptr, col, meanb, NNODES);
    k_gemm7<128, __hip_bfloat16, 1, 1><<<gemmBlocks, 1024, 0, stream>>>(meanb, xb, Wp0,
        blv[0], g[0], bb[0], rm[0], rv[0], h0, h0f8, NNODES);

    // layer 1 (KH=256): fp8 gather (CPL=16, R=4, U=4 -> 16 in flight)
    k_meanf8<256, 4><<<meanBlocks, 256, 0, stream>>>(h0f8, rowptr, col, meanb, NNODES);
    k_gemm7<256, __hip_bfloat16, 1, 1><<<gemmBlocks, 1024, 0, stream>>>(meanb, h0, Wp1,
        blv[1], g[1], bb[1], rm[1], rv[1], h1, h1f8, NNODES);

    // layer 2 (KH=256, no relu) -> f32 d_out
    k_meanf8<256, 4><<<gemmBlocks * 0 + meanBlocks, 256, 0, stream>>>(h1f8, rowptr, col, meanb, NNODES);
    k_gemm7<256, float, 0, 0><<<gemmBlocks, 1024, 0, stream>>>(meanb, h1, Wp2,
        blv[2], g[2], bb[2], rm[2], rv[2], (float*)d_out, (unsigned char*)nullptr, NNODES);
}